// Round 9
// baseline (1327.381 us; speedup 1.0000x reference)
//
#include <hip/hip_runtime.h>
#include <math.h>

#define C 128

typedef unsigned short u16;
typedef __attribute__((ext_vector_type(8))) short short8;
typedef __attribute__((ext_vector_type(4))) float f32x4;

__device__ __forceinline__ float gelu_f(float v) {
    return 0.5f * v * (1.0f + erff(v * 0.70710678118654752f));
}

__device__ __forceinline__ u16 f2bf(float f) {
    unsigned u = __float_as_uint(f);
    unsigned r = (u + 0x7fffu + ((u >> 16) & 1u)) >> 16;
    return (u16)r;
}
__device__ __forceinline__ float b2f(u16 u) {
    return __uint_as_float(((unsigned)u) << 16);
}

// ---------------------------------------------------------------------------
// Weight prep (unchanged, verified r5)
// ---------------------------------------------------------------------------
__global__ void prep_weights_kernel(const float* __restrict__ self_w,
                                    const float* __restrict__ self_b,
                                    const float* __restrict__ neigh_w,
                                    const float* __restrict__ neigh_b,
                                    const float* __restrict__ gate_w1,
                                    const float* __restrict__ gate_b1,
                                    float* __restrict__ Wc, float* __restrict__ bc,
                                    float* __restrict__ Wn1, float* __restrict__ bv,
                                    int L_) {
    const int y = blockIdx.y;
    const int i = blockIdx.x;
    const int j = threadIdx.x;
    if (y < L_) {
        const int l = y;
        const float* gw = gate_w1 + (size_t)l * 256 * C;  // top half
        if (i < C) {
            const float* swr = self_w + (size_t)l * C * C + (size_t)i * C;
            float s = 0.f;
            for (int k = 0; k < C; ++k) s += swr[k] * gw[k * C + j];
            Wc[(size_t)l * C * C + (size_t)i * C + j] = s;
        } else {
            const float* sbr = self_b + (size_t)l * C;
            float s = gate_b1[(size_t)l * C + j];
            for (int k = 0; k < C; ++k) s += sbr[k] * gw[k * C + j];
            bc[(size_t)l * C + j] = s;
        }
    } else {
        const int l = y - L_;
        const float* gw = gate_w1 + (size_t)l * 256 * C + (size_t)C * C;  // bottom half
        if (i < C) {
            const float* nwr = neigh_w + (size_t)l * C * C + (size_t)i * C;
            float s = 0.f;
            for (int k = 0; k < C; ++k) s += nwr[k] * gw[k * C + j];
            Wn1[(size_t)l * C * C + (size_t)i * C + j] = s;
        } else {
            const float* nbr = neigh_b + (size_t)l * C;
            float s = 0.f;
            for (int k = 0; k < C; ++k) s += nbr[k] * gw[k * C + j];
            bv[(size_t)l * C + j] = s;
        }
    }
}

// mats: 0=lw2, 1+l=gw2[l], 3+l=Wc[l], 5+l=Wn1[l]   (Wt[col][k] transposed planes)
__global__ void wsplit_kernel(const float* __restrict__ lw2, const float* __restrict__ gw2,
                              const float* __restrict__ Wc, const float* __restrict__ Wn1,
                              u16* __restrict__ wh, u16* __restrict__ wl) {
    const int col = blockIdx.x;
    const int mat = blockIdx.y;
    const int k = threadIdx.x;
    const float* src;
    if (mat == 0)      src = lw2;
    else if (mat <= 2) src = gw2 + (size_t)(mat - 1) * 16384;
    else if (mat <= 4) src = Wc + (size_t)(mat - 3) * 16384;
    else               src = Wn1 + (size_t)(mat - 5) * 16384;
    float v = src[k * C + col];
    u16 hi = f2bf(v);
    size_t di = (size_t)mat * 16384 + (size_t)col * C + k;
    wh[di] = hi;
    wl[di] = f2bf(v - b2f(hi));
}

__global__ void lift_hidden_kernel(const float* __restrict__ x,
                                   const float* __restrict__ w1,
                                   const float* __restrict__ b1,
                                   u16* __restrict__ oh, u16* __restrict__ ol, int N) {
    int idx = blockIdx.x * 256 + threadIdx.x;
    if (idx >= N * C) return;
    int n = idx >> 7, c = idx & 127;
    const float* xr = x + n * 9 + 3;
    float s = b1[c];
#pragma unroll
    for (int f = 0; f < 6; ++f) s += xr[f] * w1[f * C + c];
    s = gelu_f(s);
    u16 hi = f2bf(s);
    oh[idx] = hi;
    ol[idx] = f2bf(s - b2f(hi));
}

// ---------------------------------------------------------------------------
// Barrier-free direct-fragment bf16x3 MFMA GEMM.
//   pre = sum_src A@W + bias[col] (+ rowscale[row]*bias2[col]); o = maybe_gelu(pre)
//   (+ resid Rh/Rl). outF: fused LayerNorm (2KB LDS stats) -> fp32; else planes.
// A,W fragments loaded straight from global (16B/lane); no staging, no LDS tiles.
// Block = 4 waves, each 64x64 output; block tile 128x128.
// ---------------------------------------------------------------------------
__global__ __launch_bounds__(256, 3)
void gemm_direct_kernel(const u16* __restrict__ A0h, const u16* __restrict__ A0l,
                        const u16* __restrict__ W0h, const u16* __restrict__ W0l,
                        const u16* __restrict__ A1h, const u16* __restrict__ A1l,
                        const u16* __restrict__ W1h, const u16* __restrict__ W1l,
                        const float* __restrict__ bias,
                        const float* __restrict__ bias2,
                        const float* __restrict__ rowscale,
                        const u16* __restrict__ Rh, const u16* __restrict__ Rl,
                        u16* __restrict__ Oh, u16* __restrict__ Ol,
                        const float* __restrict__ lng, const float* __restrict__ lnb,
                        float* __restrict__ outF,
                        int M, int nsrc, int act) {
    __shared__ float2 ldsS[128][2];   // LN per-row (sum, sumsq) per wc-half
    const int t = threadIdx.x;
    const int lane = t & 63;
    const int w = t >> 6;
    const int wr = w >> 1, wc = w & 1;
    const int m0 = blockIdx.x * 128;
    const int kg = lane >> 4;          // 0..3
    const int l15 = lane & 15;
    const int kgo = kg * 8;            // k element offset of this lane's fragment

    int aOff[4], wOff[4];
#pragma unroll
    for (int m = 0; m < 4; ++m) {
        int grow = m0 + wr * 64 + m * 16 + l15;
        if (grow >= M) grow = M - 1;
        aOff[m] = grow * C + kgo;
    }
#pragma unroll
    for (int n = 0; n < 4; ++n) {
        int col = wc * 64 + n * 16 + l15;
        wOff[n] = col * C + kgo;
    }

    f32x4 acc[4][4];
#pragma unroll
    for (int m = 0; m < 4; ++m)
#pragma unroll
        for (int n = 0; n < 4; ++n) acc[m][n] = (f32x4)(0.f);

    for (int sidx = 0; sidx < nsrc; ++sidx) {
        const u16* Ah = sidx ? A1h : A0h;
        const u16* Al = sidx ? A1l : A0l;
        const u16* Wh = sidx ? W1h : W0h;
        const u16* Wl = sidx ? W1l : W0l;
#pragma unroll
        for (int ks = 0; ks < 4; ++ks) {
            const int ko = ks * 32;
            short8 ah[4], al[4], bh[4], bl[4];
#pragma unroll
            for (int m = 0; m < 4; ++m) {
                ah[m] = *(const short8*)(Ah + aOff[m] + ko);
                al[m] = *(const short8*)(Al + aOff[m] + ko);
            }
#pragma unroll
            for (int n = 0; n < 4; ++n) {
                bh[n] = *(const short8*)(Wh + wOff[n] + ko);
                bl[n] = *(const short8*)(Wl + wOff[n] + ko);
            }
#pragma unroll
            for (int m = 0; m < 4; ++m)
#pragma unroll
                for (int n = 0; n < 4; ++n)
                    acc[m][n] = __builtin_amdgcn_mfma_f32_16x16x32_bf16(ah[m], bh[n], acc[m][n], 0, 0, 0);
#pragma unroll
            for (int m = 0; m < 4; ++m)
#pragma unroll
                for (int n = 0; n < 4; ++n)
                    acc[m][n] = __builtin_amdgcn_mfma_f32_16x16x32_bf16(al[m], bh[n], acc[m][n], 0, 0, 0);
#pragma unroll
            for (int m = 0; m < 4; ++m)
#pragma unroll
                for (int n = 0; n < 4; ++n)
                    acc[m][n] = __builtin_amdgcn_mfma_f32_16x16x32_bf16(ah[m], bl[n], acc[m][n], 0, 0, 0);
        }
    }

    // ---- epilogue: bias (+rowscale*bias2) (+gelu), in-place into acc ----
    float bj[4], b2j[4];
#pragma unroll
    for (int n = 0; n < 4; ++n) {
        bj[n] = bias[wc * 64 + n * 16 + l15];
        b2j[n] = bias2 ? bias2[wc * 64 + n * 16 + l15] : 0.f;
    }
#pragma unroll
    for (int m = 0; m < 4; ++m)
#pragma unroll
        for (int r = 0; r < 4; ++r) {
            int grow = m0 + wr * 64 + m * 16 + kg * 4 + r;
            float rs_ = (bias2 && grow < M) ? rowscale[grow] : 0.f;
#pragma unroll
            for (int n = 0; n < 4; ++n) {
                float o = acc[m][n][r] + bj[n] + rs_ * b2j[n];
                if (act) o = gelu_f(o);
                acc[m][n][r] = o;
            }
        }

    if (!outF) {
        // plane output (+ optional residual)
#pragma unroll
        for (int m = 0; m < 4; ++m)
#pragma unroll
            for (int r = 0; r < 4; ++r) {
                int grow = m0 + wr * 64 + m * 16 + kg * 4 + r;
                if (grow < M) {
#pragma unroll
                    for (int n = 0; n < 4; ++n) {
                        int col = wc * 64 + n * 16 + l15;
                        size_t idx = (size_t)grow * C + col;
                        float o = acc[m][n][r];
                        if (Rh) o += b2f(Rh[idx]) + b2f(Rl[idx]);
                        u16 hi = f2bf(o);
                        Oh[idx] = hi;
                        Ol[idx] = f2bf(o - b2f(hi));
                    }
                }
            }
    } else {
        // fused LayerNorm: residual add + per-row stats -> 2KB LDS -> normalize
#pragma unroll
        for (int m = 0; m < 4; ++m)
#pragma unroll
            for (int r = 0; r < 4; ++r) {
                int rowl = wr * 64 + m * 16 + kg * 4 + r;
                int grow = m0 + rowl;
                bool ok = grow < M;
                float s1 = 0.f, s2 = 0.f;
#pragma unroll
                for (int n = 0; n < 4; ++n) {
                    int col = wc * 64 + n * 16 + l15;
                    size_t idx = (size_t)grow * C + col;
                    float o = acc[m][n][r];
                    if (ok && Rh) o += b2f(Rh[idx]) + b2f(Rl[idx]);
                    acc[m][n][r] = o;
                    s1 += o;
                    s2 += o * o;
                }
#pragma unroll
                for (int mk = 1; mk < 16; mk <<= 1) {
                    s1 += __shfl_xor(s1, mk, 64);
                    s2 += __shfl_xor(s2, mk, 64);
                }
                if (l15 == 0) ldsS[rowl][wc] = make_float2(s1, s2);
            }
        __syncthreads();
        float gj[4], bbj[4];
#pragma unroll
        for (int n = 0; n < 4; ++n) {
            gj[n] = lng[wc * 64 + n * 16 + l15];
            bbj[n] = lnb[wc * 64 + n * 16 + l15];
        }
#pragma unroll
        for (int m = 0; m < 4; ++m)
#pragma unroll
            for (int r = 0; r < 4; ++r) {
                int rowl = wr * 64 + m * 16 + kg * 4 + r;
                int grow = m0 + rowl;
                float2 pa = ldsS[rowl][0];
                float2 pb = ldsS[rowl][1];
                float mu = (pa.x + pb.x) * (1.f / 128.f);
                float var = (pa.y + pb.y) * (1.f / 128.f) - mu * mu;
                float rsq = 1.f / sqrtf(var + 1e-5f);
                if (grow < M) {
#pragma unroll
                    for (int n = 0; n < 4; ++n) {
                        int col = wc * 64 + n * 16 + l15;
                        outF[(size_t)grow * C + col] =
                            (acc[m][n][r] - mu) * rsq * gj[n] + bbj[n];
                    }
                }
            }
    }
}

// ---------------------------------------------------------------------------
// CSR build (unchanged, verified)
// ---------------------------------------------------------------------------
__global__ void zero_i32_kernel(int* __restrict__ p, int n) {
    int i = blockIdx.x * 256 + threadIdx.x;
    if (i < n) p[i] = 0;
}

__global__ void deg_count_kernel(const int* __restrict__ row, int* __restrict__ deg, int E) {
    int e = blockIdx.x * 256 + threadIdx.x;
    if (e < E) atomicAdd(&deg[row[e]], 1);
}

__global__ void scan_chunk_kernel(const int* __restrict__ deg, int* __restrict__ offs,
                                  int* __restrict__ part, int N) {
    __shared__ int ts[256];
    const int t = threadIdx.x;
    const int base = blockIdx.x * 1024 + t * 4;
    int v0 = (base + 0 < N) ? deg[base + 0] : 0;
    int v1 = (base + 1 < N) ? deg[base + 1] : 0;
    int v2 = (base + 2 < N) ? deg[base + 2] : 0;
    int v3 = (base + 3 < N) ? deg[base + 3] : 0;
    int l0 = v0, l1 = l0 + v1, l2 = l1 + v2, l3 = l2 + v3;
    ts[t] = l3;
    __syncthreads();
    for (int d = 1; d < 256; d <<= 1) {
        int add = (t >= d) ? ts[t - d] : 0;
        __syncthreads();
        ts[t] += add;
        __syncthreads();
    }
    int tex = ts[t] - l3;
    if (base + 0 < N) offs[base + 1] = tex + l0;
    if (base + 1 < N) offs[base + 2] = tex + l1;
    if (base + 2 < N) offs[base + 3] = tex + l2;
    if (base + 3 < N) offs[base + 4] = tex + l3;
    if (t == 255) part[blockIdx.x] = ts[255];
}

__global__ void scan_partials_kernel(int* __restrict__ part, int n) {
    __shared__ int s[128];
    const int t = threadIdx.x;
    int v = (t < n) ? part[t] : 0;
    s[t] = v;
    __syncthreads();
    for (int d = 1; d < 128; d <<= 1) {
        int add = (t >= d) ? s[t - d] : 0;
        __syncthreads();
        s[t] += add;
        __syncthreads();
    }
    if (t < n) part[t] = s[t] - v;
}

__global__ void scan_add_kernel(int* __restrict__ offs, const int* __restrict__ part,
                                int* __restrict__ cursor, int N) {
    const int t = threadIdx.x;
    const int base = blockIdx.x * 1024 + t * 4;
    const int add = part[blockIdx.x];
#pragma unroll
    for (int j = 0; j < 4; ++j) {
        int i = base + j;
        if (i < N) {
            int v = offs[i + 1] + add;
            offs[i + 1] = v;
            if (i + 1 < N) cursor[i + 1] = v;
        }
    }
    if (blockIdx.x == 0 && t == 0) {
        offs[0] = 0;
        cursor[0] = 0;
    }
}

__global__ void fill_kernel(const int* __restrict__ row, const int* __restrict__ col,
                            const float* __restrict__ ev, int* __restrict__ cursor,
                            int2* __restrict__ epack, int E) {
    int e = blockIdx.x * 256 + threadIdx.x;
    if (e >= E) return;
    int r = row[e];
    int pos = atomicAdd(&cursor[r], 1);
    int2 p;
    p.x = col[e];
    p.y = __float_as_int(ev[e]);
    epack[pos] = p;
}

// ---------------------------------------------------------------------------
// Aggregation (gather), unrolled x4: aggrH[d]=sum ev*h[col], sumev[d]=sum ev
// ---------------------------------------------------------------------------
__global__ __launch_bounds__(256)
void aggregate_kernel(const u16* __restrict__ nh, const u16* __restrict__ nl,
                      const int* __restrict__ offs, const int2* __restrict__ epack,
                      u16* __restrict__ oh, u16* __restrict__ ol,
                      float* __restrict__ sumev, int N) {
    const int lane = threadIdx.x & 63;
    const int node = (blockIdx.x << 2) + (threadIdx.x >> 6);
    if (node >= N) return;
    const int s = offs[node], e = offs[node + 1];
    const int ch = lane << 1;
    float a0x = 0.f, a0y = 0.f, a1x = 0.f, a1y = 0.f;
    float a2x = 0.f, a2y = 0.f, a3x = 0.f, a3y = 0.f;
    float ssum = 0.f;
    int i = s;
    for (; i + 4 <= e; i += 4) {
        int2 p0 = epack[i];
        int2 p1 = epack[i + 1];
        int2 p2 = epack[i + 2];
        int2 p3 = epack[i + 3];
        float v0 = __int_as_float(p0.y), v1 = __int_as_float(p1.y);
        float v2 = __int_as_float(p2.y), v3 = __int_as_float(p3.y);
        ushort2 h0 = *(const ushort2*)&nh[(size_t)p0.x * C + ch];
        ushort2 h1 = *(const ushort2*)&nh[(size_t)p1.x * C + ch];
        ushort2 h2 = *(const ushort2*)&nh[(size_t)p2.x * C + ch];
        ushort2 h3 = *(const ushort2*)&nh[(size_t)p3.x * C + ch];
        ushort2 q0 = *(const ushort2*)&nl[(size_t)p0.x * C + ch];
        ushort2 q1 = *(const ushort2*)&nl[(size_t)p1.x * C + ch];
        ushort2 q2 = *(const ushort2*)&nl[(size_t)p2.x * C + ch];
        ushort2 q3 = *(const ushort2*)&nl[(size_t)p3.x * C + ch];
        a0x += v0 * (b2f(h0.x) + b2f(q0.x)); a0y += v0 * (b2f(h0.y) + b2f(q0.y));
        a1x += v1 * (b2f(h1.x) + b2f(q1.x)); a1y += v1 * (b2f(h1.y) + b2f(q1.y));
        a2x += v2 * (b2f(h2.x) + b2f(q2.x)); a2y += v2 * (b2f(h2.y) + b2f(q2.y));
        a3x += v3 * (b2f(h3.x) + b2f(q3.x)); a3y += v3 * (b2f(h3.y) + b2f(q3.y));
        ssum += (v0 + v1) + (v2 + v3);
    }
    for (; i < e; ++i) {
        int2 p = epack[i];
        float v = __int_as_float(p.y);
        ushort2 h0 = *(const ushort2*)&nh[(size_t)p.x * C + ch];
        ushort2 q0 = *(const ushort2*)&nl[(size_t)p.x * C + ch];
        a0x += v * (b2f(h0.x) + b2f(q0.x));
        a0y += v * (b2f(h0.y) + b2f(q0.y));
        ssum += v;
    }
    float sx = (a0x + a1x) + (a2x + a3x);
    float sy = (a0y + a1y) + (a2y + a3y);
    ushort2 ho, lo;
    ho.x = f2bf(sx); ho.y = f2bf(sy);
    lo.x = f2bf(sx - b2f(ho.x)); lo.y = f2bf(sy - b2f(ho.y));
    size_t idx = (size_t)node * C + ch;
    *(ushort2*)&oh[idx] = ho;
    *(ushort2*)&ol[idx] = lo;
    if (lane == 0) sumev[node] = ssum;
}

// ---------------------------------------------------------------------------
extern "C" void kernel_launch(void* const* d_in, const int* in_sizes, int n_in,
                              void* d_out, int out_size, void* d_ws, size_t ws_size,
                              hipStream_t stream) {
    const float* x    = (const float*)d_in[0];
    const int*   ei   = (const int*)d_in[1];
    const float* ev   = (const float*)d_in[2];
    const float* lw1  = (const float*)d_in[3];
    const float* lb1  = (const float*)d_in[4];
    const float* lw2  = (const float*)d_in[5];
    const float* lb2  = (const float*)d_in[6];
    const float* sw   = (const float*)d_in[7];
    const float* sb   = (const float*)d_in[8];
    const float* nw   = (const float*)d_in[9];
    const float* nbi  = (const float*)d_in[10];
    const float* gw1  = (const float*)d_in[11];
    const float* gb1  = (const float*)d_in[12];
    const float* gw2  = (const float*)d_in[13];
    const float* gb2  = (const float*)d_in[14];
    const float* ng   = (const float*)d_in[15];
    const float* nbt  = (const float*)d_in[16];

    const int N = in_sizes[0] / 9;
    const int E = in_sizes[2];
    const int L = in_sizes[7] / (C * C);
    const int* row = ei;
    const int* col = ei + E;

    float* out = (float*)d_out;

    // workspace carve
    char* p = (char*)d_ws;
    u16* Hh = (u16*)p; p += (size_t)N * C * 2;   // h planes
    u16* Hl = (u16*)p; p += (size_t)N * C * 2;
    u16* Bh = (u16*)p; p += (size_t)N * C * 2;   // lift hid / u1 planes
    u16* Bl = (u16*)p; p += (size_t)N * C * 2;
    u16* Ch = (u16*)p; p += (size_t)N * C * 2;   // aggrH planes
    u16* Cl = (u16*)p; p += (size_t)N * C * 2;
    int2* epack = (int2*)p; p += (size_t)E * sizeof(int2);
    float* Wc  = (float*)p; p += (size_t)L * C * C * sizeof(float);
    float* Wn1 = (float*)p; p += (size_t)L * C * C * sizeof(float);
    float* bc  = (float*)p; p += (size_t)L * C * sizeof(float);
    float* bv  = (float*)p; p += (size_t)L * C * sizeof(float);
    float* sumev = (float*)p; p += (size_t)N * sizeof(float);
    u16* wh = (u16*)p; p += (size_t)7 * C * C * 2;
    u16* wl = (u16*)p; p += (size_t)7 * C * C * 2;
    int* deg    = (int*)p; p += (size_t)N * sizeof(int);
    int* offs   = (int*)p; p += (size_t)(N + 1) * sizeof(int);
    int* cursor = (int*)p; p += (size_t)N * sizeof(int);
    int* part   = (int*)p; p += 1024 * sizeof(int);

    const int NB_SCAN = (N + 1023) / 1024;
    const int GB_NODE = (N + 3) / 4;
    const int GB_EDGE = (E + 255) / 256;
    const int GB_GEMM = (N + 127) / 128;

    prep_weights_kernel<<<dim3(C + 1, 2 * L), C, 0, stream>>>(
        sw, sb, nw, nbi, gw1, gb1, Wc, bc, Wn1, bv, L);
    wsplit_kernel<<<dim3(C, 7), C, 0, stream>>>(lw2, gw2, Wc, Wn1, wh, wl);

    // lift
    lift_hidden_kernel<<<(N * C + 255) / 256, 256, 0, stream>>>(x, lw1, lb1, Bh, Bl, N);
    gemm_direct_kernel<<<GB_GEMM, 256, 0, stream>>>(
        Bh, Bl, wh, wl, nullptr, nullptr, nullptr, nullptr,
        lb2, nullptr, nullptr, nullptr, nullptr, Hh, Hl,
        nullptr, nullptr, nullptr, N, 1, 0);

    // CSR build
    zero_i32_kernel<<<(N + 255) / 256, 256, 0, stream>>>(deg, N);
    deg_count_kernel<<<GB_EDGE, 256, 0, stream>>>(row, deg, E);
    scan_chunk_kernel<<<NB_SCAN, 256, 0, stream>>>(deg, offs, part, N);
    scan_partials_kernel<<<1, 128, 0, stream>>>(part, NB_SCAN);
    scan_add_kernel<<<NB_SCAN, 256, 0, stream>>>(offs, part, cursor, N);
    fill_kernel<<<GB_EDGE, 256, 0, stream>>>(row, col, ev, cursor, epack, E);

    for (int l = 0; l < L; ++l) {
        const u16* g2h = wh + (size_t)(1 + l) * 16384;
        const u16* g2l = wl + (size_t)(1 + l) * 16384;
        const u16* wch = wh + (size_t)(3 + l) * 16384;
        const u16* wcl = wl + (size_t)(3 + l) * 16384;
        const u16* n1h = wh + (size_t)(5 + l) * 16384;
        const u16* n1l = wl + (size_t)(5 + l) * 16384;
        const bool last = (l == L - 1);

        // aggrH = CSR-gather(h), sumev
        aggregate_kernel<<<GB_NODE, 256, 0, stream>>>(Hh, Hl, offs, epack, Ch, Cl, sumev, N);
        // u1 = gelu(h@Wc + aggrH@Wn1 + bc + sumev*bv)  -> B planes
        gemm_direct_kernel<<<GB_GEMM, 256, 0, stream>>>(
            Hh, Hl, wch, wcl, Ch, Cl, n1h, n1l,
            bc + (size_t)l * C, bv + (size_t)l * C, sumev,
            nullptr, nullptr, Bh, Bl,
            nullptr, nullptr, nullptr, N, 2, 1);
        // h' = h + u1@gw2 + gb2 ; last layer: fused LN -> fp32 out
        gemm_direct_kernel<<<GB_GEMM, 256, 0, stream>>>(
            Bh, Bl, g2h, g2l, nullptr, nullptr, nullptr, nullptr,
            gb2 + (size_t)l * C, nullptr, nullptr,
            Hh, Hl,
            last ? nullptr : Hh, last ? nullptr : Hl,
            last ? ng : nullptr, last ? nbt : nullptr, last ? out : nullptr,
            N, 1, 0);
    }
}

// Round 10
// 818.311 us; speedup vs baseline: 1.6221x; 1.6221x over previous
//
#include <hip/hip_runtime.h>
#include <math.h>

#define C 128

typedef unsigned short u16;
typedef __attribute__((ext_vector_type(8))) short short8;
typedef __attribute__((ext_vector_type(4))) float f32x4;

__device__ __forceinline__ float gelu_f(float v) {
    return 0.5f * v * (1.0f + erff(v * 0.70710678118654752f));
}

__device__ __forceinline__ u16 f2bf(float f) {
    unsigned u = __float_as_uint(f);
    unsigned r = (u + 0x7fffu + ((u >> 16) & 1u)) >> 16;
    return (u16)r;
}
__device__ __forceinline__ float b2f(u16 u) {
    return __uint_as_float(((unsigned)u) << 16);
}

__device__ __forceinline__ void g2lds16(const void* g, void* l) {
    __builtin_amdgcn_global_load_lds(
        (const __attribute__((address_space(1))) unsigned int*)g,
        (__attribute__((address_space(3))) unsigned int*)l, 16, 0, 0);
}

// ---------------------------------------------------------------------------
// Weight prep (verified r5)
// ---------------------------------------------------------------------------
__global__ void prep_weights_kernel(const float* __restrict__ self_w,
                                    const float* __restrict__ self_b,
                                    const float* __restrict__ neigh_w,
                                    const float* __restrict__ neigh_b,
                                    const float* __restrict__ gate_w1,
                                    const float* __restrict__ gate_b1,
                                    float* __restrict__ Wc, float* __restrict__ bc,
                                    float* __restrict__ Wn1, float* __restrict__ bv,
                                    int L_) {
    const int y = blockIdx.y;
    const int i = blockIdx.x;
    const int j = threadIdx.x;
    if (y < L_) {
        const int l = y;
        const float* gw = gate_w1 + (size_t)l * 256 * C;  // top half
        if (i < C) {
            const float* swr = self_w + (size_t)l * C * C + (size_t)i * C;
            float s = 0.f;
            for (int k = 0; k < C; ++k) s += swr[k] * gw[k * C + j];
            Wc[(size_t)l * C * C + (size_t)i * C + j] = s;
        } else {
            const float* sbr = self_b + (size_t)l * C;
            float s = gate_b1[(size_t)l * C + j];
            for (int k = 0; k < C; ++k) s += sbr[k] * gw[k * C + j];
            bc[(size_t)l * C + j] = s;
        }
    } else {
        const int l = y - L_;
        const float* gw = gate_w1 + (size_t)l * 256 * C + (size_t)C * C;  // bottom half
        if (i < C) {
            const float* nwr = neigh_w + (size_t)l * C * C + (size_t)i * C;
            float s = 0.f;
            for (int k = 0; k < C; ++k) s += nwr[k] * gw[k * C + j];
            Wn1[(size_t)l * C * C + (size_t)i * C + j] = s;
        } else {
            const float* nbr = neigh_b + (size_t)l * C;
            float s = 0.f;
            for (int k = 0; k < C; ++k) s += nbr[k] * gw[k * C + j];
            bv[(size_t)l * C + j] = s;
        }
    }
}

// mats: 0=lw2, 1+l=gw2[l], 3+l=Wc[l], 5+l=Wn1[l]   (Wt[col][k] transposed planes)
__global__ void wsplit_kernel(const float* __restrict__ lw2, const float* __restrict__ gw2,
                              const float* __restrict__ Wc, const float* __restrict__ Wn1,
                              u16* __restrict__ wh, u16* __restrict__ wl) {
    const int col = blockIdx.x;
    const int mat = blockIdx.y;
    const int k = threadIdx.x;
    const float* src;
    if (mat == 0)      src = lw2;
    else if (mat <= 2) src = gw2 + (size_t)(mat - 1) * 16384;
    else if (mat <= 4) src = Wc + (size_t)(mat - 3) * 16384;
    else               src = Wn1 + (size_t)(mat - 5) * 16384;
    float v = src[k * C + col];
    u16 hi = f2bf(v);
    size_t di = (size_t)mat * 16384 + (size_t)col * C + k;
    wh[di] = hi;
    wl[di] = f2bf(v - b2f(hi));
}

__global__ void lift_hidden_kernel(const float* __restrict__ x,
                                   const float* __restrict__ w1,
                                   const float* __restrict__ b1,
                                   u16* __restrict__ oh, u16* __restrict__ ol, int N) {
    int idx = blockIdx.x * 256 + threadIdx.x;
    if (idx >= N * C) return;
    int n = idx >> 7, c = idx & 127;
    const float* xr = x + n * 9 + 3;
    float s = b1[c];
#pragma unroll
    for (int f = 0; f < 6; ++f) s += xr[f] * w1[f * C + c];
    s = gelu_f(s);
    u16 hi = f2bf(s);
    oh[idx] = hi;
    ol[idx] = f2bf(s - b2f(hi));
}

// ---------------------------------------------------------------------------
// Staging helper: one half-plane (128 rows x 64 u16) -> LDS plane p.
// Linear LDS dest, pre-swizzled global source (chunk cl = (chunk&7)^(row&7)).
// Verified (r8 run, absmax ok).
// ---------------------------------------------------------------------------
__device__ __forceinline__ void stage_plane(const u16* __restrict__ g, char* lds_base,
                                            int p, int t, int kh, int m0, int M,
                                            bool clampA) {
#pragma unroll
    for (int it = 0; it < 4; ++it) {
        int chunk = it * 256 + t;            // 0..1023
        int row = chunk >> 3;                // 0..127
        int cl = (chunk & 7) ^ (row & 7);    // pre-swizzled source chunk
        int grow = clampA ? ((m0 + row < M) ? m0 + row : M - 1) : row;
        const u16* src = g + (size_t)grow * C + kh * 64 + cl * 8;
        g2lds16(src, lds_base + (size_t)p * 16384 + chunk * 16);
    }
}

// ---------------------------------------------------------------------------
// LDS-staged bf16x3 MFMA GEMM, register-lean inner loop (b-frags per n).
//   pre = sum_src A@W + bias[col] (+ rowscale[row]*bias2[col]); o = maybe_gelu
//   (+ resid Rh/Rl). outF: fused LayerNorm via per-row stats -> fp32; else planes.
// BM=128, BN=128, BK=64, 256 thr = 4 waves (64x64 each), 64KB LDS, 2 blk/CU.
// ---------------------------------------------------------------------------
__global__ __launch_bounds__(256, 2)
void gemm_mfma_kernel(const u16* __restrict__ A0h, const u16* __restrict__ A0l,
                      const u16* __restrict__ W0h, const u16* __restrict__ W0l,
                      const u16* __restrict__ A1h, const u16* __restrict__ A1l,
                      const u16* __restrict__ W1h, const u16* __restrict__ W1l,
                      const float* __restrict__ bias,
                      const float* __restrict__ bias2,
                      const float* __restrict__ rowscale,
                      const u16* __restrict__ Rh, const u16* __restrict__ Rl,
                      u16* __restrict__ Oh, u16* __restrict__ Ol,
                      const float* __restrict__ lng, const float* __restrict__ lnb,
                      float* __restrict__ outF,
                      int M, int nsrc, int act) {
    __shared__ __align__(16) char smem[65536];
    const int t = threadIdx.x;
    const int lane = t & 63;
    const int w = t >> 6;
    const int wr = w >> 1, wc = w & 1;
    const int m0 = blockIdx.x * 128;
    const int kg = lane >> 4;
    const int swz = lane & 7;
    const int l15 = lane & 15;

    f32x4 acc[4][4];
#pragma unroll
    for (int m = 0; m < 4; ++m)
#pragma unroll
        for (int n = 0; n < 4; ++n) acc[m][n] = (f32x4)(0.f);

    for (int sidx = 0; sidx < nsrc; ++sidx) {
        const u16* Ah_ = sidx ? A1h : A0h;
        const u16* Al_ = sidx ? A1l : A0l;
        const u16* Wh_ = sidx ? W1h : W0h;
        const u16* Wl_ = sidx ? W1l : W0l;
        for (int kh = 0; kh < 2; ++kh) {
            stage_plane(Ah_, smem, 0, t, kh, m0, M, true);
            stage_plane(Al_, smem, 1, t, kh, m0, M, true);
            stage_plane(Wh_, smem, 2, t, kh, m0, M, false);
            stage_plane(Wl_, smem, 3, t, kh, m0, M, false);
            __syncthreads();
#pragma unroll
            for (int s = 0; s < 2; ++s) {
                const int ci = ((s * 4 + kg) ^ swz) * 16;
                short8 ah[4], al[4];
#pragma unroll
                for (int m = 0; m < 4; ++m) {
                    int ro = (wr * 64 + m * 16 + l15) * 128;
                    ah[m] = *(const short8*)(smem + ro + ci);
                    al[m] = *(const short8*)(smem + 16384 + ro + ci);
                }
#pragma unroll
                for (int n = 0; n < 4; ++n) {
                    int ro = (wc * 64 + n * 16 + l15) * 128;
                    short8 bh = *(const short8*)(smem + 32768 + ro + ci);
                    short8 bl = *(const short8*)(smem + 49152 + ro + ci);
#pragma unroll
                    for (int m = 0; m < 4; ++m)
                        acc[m][n] = __builtin_amdgcn_mfma_f32_16x16x32_bf16(ah[m], bh, acc[m][n], 0, 0, 0);
#pragma unroll
                    for (int m = 0; m < 4; ++m)
                        acc[m][n] = __builtin_amdgcn_mfma_f32_16x16x32_bf16(al[m], bh, acc[m][n], 0, 0, 0);
#pragma unroll
                    for (int m = 0; m < 4; ++m)
                        acc[m][n] = __builtin_amdgcn_mfma_f32_16x16x32_bf16(ah[m], bl, acc[m][n], 0, 0, 0);
                }
            }
            __syncthreads();
        }
    }

    // ---- epilogue: bias (+rowscale*bias2) (+gelu) ----
    float bj[4], b2j[4];
#pragma unroll
    for (int n = 0; n < 4; ++n) {
        bj[n] = bias[wc * 64 + n * 16 + l15];
        b2j[n] = bias2 ? bias2[wc * 64 + n * 16 + l15] : 0.f;
    }
#pragma unroll
    for (int m = 0; m < 4; ++m)
#pragma unroll
        for (int r = 0; r < 4; ++r) {
            int grow = m0 + wr * 64 + m * 16 + kg * 4 + r;
            float rs_ = (bias2 && grow < M) ? rowscale[grow] : 0.f;
#pragma unroll
            for (int n = 0; n < 4; ++n) {
                float o = acc[m][n][r] + bj[n] + rs_ * b2j[n];
                if (act) o = gelu_f(o);
                acc[m][n][r] = o;
            }
        }

    if (!outF) {
        // plane output (+ optional residual)
#pragma unroll
        for (int m = 0; m < 4; ++m)
#pragma unroll
            for (int r = 0; r < 4; ++r) {
                int grow = m0 + wr * 64 + m * 16 + kg * 4 + r;
                if (grow < M) {
#pragma unroll
                    for (int n = 0; n < 4; ++n) {
                        int col = wc * 64 + n * 16 + l15;
                        size_t idx = (size_t)grow * C + col;
                        float o = acc[m][n][r];
                        if (Rh) o += b2f(Rh[idx]) + b2f(Rl[idx]);
                        u16 hi = f2bf(o);
                        Oh[idx] = hi;
                        Ol[idx] = f2bf(o - b2f(hi));
                    }
                }
            }
    } else {
        // fused LayerNorm: residual add + per-row stats (reuse smem) -> normalize
        float2* ldsS = (float2*)smem;   // [128][2] (sum, sumsq) per wc-half
#pragma unroll
        for (int m = 0; m < 4; ++m)
#pragma unroll
            for (int r = 0; r < 4; ++r) {
                int rowl = wr * 64 + m * 16 + kg * 4 + r;
                int grow = m0 + rowl;
                bool ok = grow < M;
                float s1 = 0.f, s2 = 0.f;
#pragma unroll
                for (int n = 0; n < 4; ++n) {
                    int col = wc * 64 + n * 16 + l15;
                    size_t idx = (size_t)grow * C + col;
                    float o = acc[m][n][r];
                    if (ok && Rh) o += b2f(Rh[idx]) + b2f(Rl[idx]);
                    acc[m][n][r] = o;
                    s1 += o;
                    s2 += o * o;
                }
#pragma unroll
                for (int mk = 1; mk < 16; mk <<= 1) {
                    s1 += __shfl_xor(s1, mk, 64);
                    s2 += __shfl_xor(s2, mk, 64);
                }
                if (l15 == 0) ldsS[rowl * 2 + wc] = make_float2(s1, s2);
            }
        __syncthreads();
        float gj[4], bbj[4];
#pragma unroll
        for (int n = 0; n < 4; ++n) {
            gj[n] = lng[wc * 64 + n * 16 + l15];
            bbj[n] = lnb[wc * 64 + n * 16 + l15];
        }
#pragma unroll
        for (int m = 0; m < 4; ++m)
#pragma unroll
            for (int r = 0; r < 4; ++r) {
                int rowl = wr * 64 + m * 16 + kg * 4 + r;
                int grow = m0 + rowl;
                float2 pa = ldsS[rowl * 2 + 0];
                float2 pb = ldsS[rowl * 2 + 1];
                float mu = (pa.x + pb.x) * (1.f / 128.f);
                float var = (pa.y + pb.y) * (1.f / 128.f) - mu * mu;
                float rsq = 1.f / sqrtf(var + 1e-5f);
                if (grow < M) {
#pragma unroll
                    for (int n = 0; n < 4; ++n) {
                        int col = wc * 64 + n * 16 + l15;
                        outF[(size_t)grow * C + col] =
                            (acc[m][n][r] - mu) * rsq * gj[n] + bbj[n];
                    }
                }
            }
    }
}

// ---------------------------------------------------------------------------
// CSR build
// ---------------------------------------------------------------------------
__global__ void zero_i32_kernel(int* __restrict__ p, int n) {
    int i = blockIdx.x * 256 + threadIdx.x;
    if (i < n) p[i] = 0;
}

__global__ void deg_count_kernel(const int* __restrict__ row, int* __restrict__ deg, int E) {
    int e = blockIdx.x * 256 + threadIdx.x;
    if (e < E) atomicAdd(&deg[row[e]], 1);
}

__global__ void scan_chunk_kernel(const int* __restrict__ deg, int* __restrict__ offs,
                                  int* __restrict__ part, int N) {
    __shared__ int ts[256];
    const int t = threadIdx.x;
    const int base = blockIdx.x * 1024 + t * 4;
    int v0 = (base + 0 < N) ? deg[base + 0] : 0;
    int v1 = (base + 1 < N) ? deg[base + 1] : 0;
    int v2 = (base + 2 < N) ? deg[base + 2] : 0;
    int v3 = (base + 3 < N) ? deg[base + 3] : 0;
    int l0 = v0, l1 = l0 + v1, l2 = l1 + v2, l3 = l2 + v3;
    ts[t] = l3;
    __syncthreads();
    for (int d = 1; d < 256; d <<= 1) {
        int add = (t >= d) ? ts[t - d] : 0;
        __syncthreads();
        ts[t] += add;
        __syncthreads();
    }
    int tex = ts[t] - l3;
    if (base + 0 < N) offs[base + 1] = tex + l0;
    if (base + 1 < N) offs[base + 2] = tex + l1;
    if (base + 2 < N) offs[base + 3] = tex + l2;
    if (base + 3 < N) offs[base + 4] = tex + l3;
    if (t == 255) part[blockIdx.x] = ts[255];
}

__global__ void scan_partials_kernel(int* __restrict__ part, int n) {
    __shared__ int s[128];
    const int t = threadIdx.x;
    int v = (t < n) ? part[t] : 0;
    s[t] = v;
    __syncthreads();
    for (int d = 1; d < 128; d <<= 1) {
        int add = (t >= d) ? s[t - d] : 0;
        __syncthreads();
        s[t] += add;
        __syncthreads();
    }
    if (t < n) part[t] = s[t] - v;
}

__global__ void scan_add_kernel(int* __restrict__ offs, const int* __restrict__ part,
                                int* __restrict__ cursor, int N) {
    const int t = threadIdx.x;
    const int base = blockIdx.x * 1024 + t * 4;
    const int add = part[blockIdx.x];
#pragma unroll
    for (int j = 0; j < 4; ++j) {
        int i = base + j;
        if (i < N) {
            int v = offs[i + 1] + add;
            offs[i + 1] = v;
            if (i + 1 < N) cursor[i + 1] = v;
        }
    }
    if (blockIdx.x == 0 && t == 0) {
        offs[0] = 0;
        cursor[0] = 0;
    }
}

// nt scatter store: bypass L2 line ownership churn on random 8B writes
__global__ void fill_kernel(const int* __restrict__ row, const int* __restrict__ col,
                            const float* __restrict__ ev, int* __restrict__ cursor,
                            int2* __restrict__ epack, int E) {
    int e = blockIdx.x * 256 + threadIdx.x;
    if (e >= E) return;
    int r = row[e];
    int pos = atomicAdd(&cursor[r], 1);
    unsigned long long pv = (unsigned)col[e] |
        ((unsigned long long)(unsigned)__float_as_int(ev[e]) << 32);
    __builtin_nontemporal_store(pv, (unsigned long long*)&epack[pos]);
}

// ---------------------------------------------------------------------------
// Aggregation (gather), unrolled x4: aggrH[d]=sum ev*h[col], sumev[d]=sum ev
// ---------------------------------------------------------------------------
__global__ __launch_bounds__(256)
void aggregate_kernel(const u16* __restrict__ nh, const u16* __restrict__ nl,
                      const int* __restrict__ offs, const int2* __restrict__ epack,
                      u16* __restrict__ oh, u16* __restrict__ ol,
                      float* __restrict__ sumev, int N) {
    const int lane = threadIdx.x & 63;
    const int node = (blockIdx.x << 2) + (threadIdx.x >> 6);
    if (node >= N) return;
    const int s = offs[node], e = offs[node + 1];
    const int ch = lane << 1;
    float a0x = 0.f, a0y = 0.f, a1x = 0.f, a1y = 0.f;
    float a2x = 0.f, a2y = 0.f, a3x = 0.f, a3y = 0.f;
    float ssum = 0.f;
    int i = s;
    for (; i + 4 <= e; i += 4) {
        int2 p0 = epack[i];
        int2 p1 = epack[i + 1];
        int2 p2 = epack[i + 2];
        int2 p3 = epack[i + 3];
        float v0 = __int_as_float(p0.y), v1 = __int_as_float(p1.y);
        float v2 = __int_as_float(p2.y), v3 = __int_as_float(p3.y);
        ushort2 h0 = *(const ushort2*)&nh[(size_t)p0.x * C + ch];
        ushort2 h1 = *(const ushort2*)&nh[(size_t)p1.x * C + ch];
        ushort2 h2 = *(const ushort2*)&nh[(size_t)p2.x * C + ch];
        ushort2 h3 = *(const ushort2*)&nh[(size_t)p3.x * C + ch];
        ushort2 q0 = *(const ushort2*)&nl[(size_t)p0.x * C + ch];
        ushort2 q1 = *(const ushort2*)&nl[(size_t)p1.x * C + ch];
        ushort2 q2 = *(const ushort2*)&nl[(size_t)p2.x * C + ch];
        ushort2 q3 = *(const ushort2*)&nl[(size_t)p3.x * C + ch];
        a0x += v0 * (b2f(h0.x) + b2f(q0.x)); a0y += v0 * (b2f(h0.y) + b2f(q0.y));
        a1x += v1 * (b2f(h1.x) + b2f(q1.x)); a1y += v1 * (b2f(h1.y) + b2f(q1.y));
        a2x += v2 * (b2f(h2.x) + b2f(q2.x)); a2y += v2 * (b2f(h2.y) + b2f(q2.y));
        a3x += v3 * (b2f(h3.x) + b2f(q3.x)); a3y += v3 * (b2f(h3.y) + b2f(q3.y));
        ssum += (v0 + v1) + (v2 + v3);
    }
    for (; i < e; ++i) {
        int2 p = epack[i];
        float v = __int_as_float(p.y);
        ushort2 h0 = *(const ushort2*)&nh[(size_t)p.x * C + ch];
        ushort2 q0 = *(const ushort2*)&nl[(size_t)p.x * C + ch];
        a0x += v * (b2f(h0.x) + b2f(q0.x));
        a0y += v * (b2f(h0.y) + b2f(q0.y));
        ssum += v;
    }
    float sx = (a0x + a1x) + (a2x + a3x);
    float sy = (a0y + a1y) + (a2y + a3y);
    ushort2 ho, lo;
    ho.x = f2bf(sx); ho.y = f2bf(sy);
    lo.x = f2bf(sx - b2f(ho.x)); lo.y = f2bf(sy - b2f(ho.y));
    size_t idx = (size_t)node * C + ch;
    *(ushort2*)&oh[idx] = ho;
    *(ushort2*)&ol[idx] = lo;
    if (lane == 0) sumev[node] = ssum;
}

// ---------------------------------------------------------------------------
extern "C" void kernel_launch(void* const* d_in, const int* in_sizes, int n_in,
                              void* d_out, int out_size, void* d_ws, size_t ws_size,
                              hipStream_t stream) {
    const float* x    = (const float*)d_in[0];
    const int*   ei   = (const int*)d_in[1];
    const float* ev   = (const float*)d_in[2];
    const float* lw1  = (const float*)d_in[3];
    const float* lb1  = (const float*)d_in[4];
    const float* lw2  = (const float*)d_in[5];
    const float* lb2  = (const float*)d_in[6];
    const float* sw   = (const float*)d_in[7];
    const float* sb   = (const float*)d_in[8];
    const float* nw   = (const float*)d_in[9];
    const float* nbi  = (const float*)d_in[10];
    const float* gw1  = (const float*)d_in[11];
    const float* gb1  = (const float*)d_in[12];
    const float* gw2  = (const float*)d_in[13];
    const float* gb2  = (const float*)d_in[14];
    const float* ng   = (const float*)d_in[15];
    const float* nbt  = (const float*)d_in[16];

    const int N = in_sizes[0] / 9;
    const int E = in_sizes[2];
    const int L = in_sizes[7] / (C * C);
    const int* row = ei;
    const int* col = ei + E;

    float* out = (float*)d_out;

    // workspace carve
    char* p = (char*)d_ws;
    u16* Hh = (u16*)p; p += (size_t)N * C * 2;   // h planes
    u16* Hl = (u16*)p; p += (size_t)N * C * 2;
    u16* Bh = (u16*)p; p += (size_t)N * C * 2;   // lift hid / u1 planes
    u16* Bl = (u16*)p; p += (size_t)N * C * 2;
    u16* Ch = (u16*)p; p += (size_t)N * C * 2;   // aggrH planes
    u16* Cl = (u16*)p; p += (size_t)N * C * 2;
    int2* epack = (int2*)p; p += (size_t)E * sizeof(int2);
    float* Wc  = (float*)p; p += (size_t)L * C * C * sizeof(float);
    float* Wn1 = (float*)p; p += (size_t)L * C * C * sizeof(float);
    float* bc  = (float*)p; p += (size_t)L * C * sizeof(float);
    float* bv  = (float*)p; p += (size_t)L * C * sizeof(float);
    float* sumev = (float*)p; p += (size_t)N * sizeof(float);
    u16* wh = (u16*)p; p += (size_t)7 * C * C * 2;
    u16* wl = (u16*)p; p += (size_t)7 * C * C * 2;
    int* deg    = (int*)p; p += (size_t)N * sizeof(int);
    int* offs   = (int*)p; p += (size_t)(N + 1) * sizeof(int);
    int* cursor = (int*)p; p += (size_t)N * sizeof(int);
    int* part   = (int*)p; p += 1024 * sizeof(int);

    const int NB_SCAN = (N + 1023) / 1024;
    const int GB_NODE = (N + 3) / 4;
    const int GB_EDGE = (E + 255) / 256;
    const int GB_GEMM = (N + 127) / 128;

    prep_weights_kernel<<<dim3(C + 1, 2 * L), C, 0, stream>>>(
        sw, sb, nw, nbi, gw1, gb1, Wc, bc, Wn1, bv, L);
    wsplit_kernel<<<dim3(C, 7), C, 0, stream>>>(lw2, gw2, Wc, Wn1, wh, wl);

    // lift
    lift_hidden_kernel<<<(N * C + 255) / 256, 256, 0, stream>>>(x, lw1, lb1, Bh, Bl, N);
    gemm_mfma_kernel<<<GB_GEMM, 256, 0, stream>>>(
        Bh, Bl, wh, wl, nullptr, nullptr, nullptr, nullptr,
        lb2, nullptr, nullptr, nullptr, nullptr, Hh, Hl,
        nullptr, nullptr, nullptr, N, 1, 0);

    // CSR build
    zero_i32_kernel<<<(N + 255) / 256, 256, 0, stream>>>(deg, N);
    deg_count_kernel<<<GB_EDGE, 256, 0, stream>>>(row, deg, E);
    scan_chunk_kernel<<<NB_SCAN, 256, 0, stream>>>(deg, offs, part, N);
    scan_partials_kernel<<<1, 128, 0, stream>>>(part, NB_SCAN);
    scan_add_kernel<<<NB_SCAN, 256, 0, stream>>>(offs, part, cursor, N);
    fill_kernel<<<GB_EDGE, 256, 0, stream>>>(row, col, ev, cursor, epack, E);

    for (int l = 0; l < L; ++l) {
        const u16* g2h = wh + (size_t)(1 + l) * 16384;
        const u16* g2l = wl + (size_t)(1 + l) * 16384;
        const u16* wch = wh + (size_t)(3 + l) * 16384;
        const u16* wcl = wl + (size_t)(3 + l) * 16384;
        const u16* n1h = wh + (size_t)(5 + l) * 16384;
        const u16* n1l = wl + (size_t)(5 + l) * 16384;
        const bool last = (l == L - 1);

        // aggrH = CSR-gather(h), sumev
        aggregate_kernel<<<GB_NODE, 256, 0, stream>>>(Hh, Hl, offs, epack, Ch, Cl, sumev, N);
        // u1 = gelu(h@Wc + aggrH@Wn1 + bc + sumev*bv)  -> B planes
        gemm_mfma_kernel<<<GB_GEMM, 256, 0, stream>>>(
            Hh, Hl, wch, wcl, Ch, Cl, n1h, n1l,
            bc + (size_t)l * C, bv + (size_t)l * C, sumev,
            nullptr, nullptr, Bh, Bl,
            nullptr, nullptr, nullptr, N, 2, 1);
        // h' = h + u1@gw2 + gb2 ; last layer: fused LN -> fp32 out
        gemm_mfma_kernel<<<GB_GEMM, 256, 0, stream>>>(
            Bh, Bl, g2h, g2l, nullptr, nullptr, nullptr, nullptr,
            gb2 + (size_t)l * C, nullptr, nullptr,
            Hh, Hl,
            last ? nullptr : Hh, last ? nullptr : Hl,
            last ? ng : nullptr, last ? nbt : nullptr, last ? out : nullptr,
            N, 1, 0);
    }
}